// Round 10
// baseline (262.268 us; speedup 1.0000x reference)
//
#include <hip/hip_runtime.h>
#include <math.h>

// Problem constants (from reference setup_inputs)
#define NB     64      // batch
#define N1V    8192    // obj points per batch
#define NPTS   (NB * N1V)
#define NV     778     // recon / gt verts
#define NVP    780     // padded to multiple of 4
#define NFACE  1538
#define NZ     64
#define NPAR   61
#define NPRIOR 204
#define PPT    8       // obj points per thread (rec/gt roles)
#define BIAS   0.0625f // 2|a||t| <= 0.06 < BIAS -> biased rec partials stay >= 0

// target halves: [0,392) and [392,780) — disjoint, both multiples of 4
#define H0_N   392
#define H1_OFF 392
#define H1_N   388
#define PRI_S  388     // prior staged at s_t[388..592) in rec-h1 blocks

// k_fused roles
#define REC_BLOCKS 512                 // (batch, chunk-of-2048, half)
#define GT_BLOCKS  512
#define CH_BLOCKS  128                 // (batch, dir)
#define NROLE_BLOCKS (REC_BLOCKS + GT_BLOCKS + CH_BLOCKS)   // 1152
#define CMB_BLOCKS 512

// ws float4 layout per batch (BATCH_F4 float4s):
//   [0,780)     gt4   (x,y,z,|t|^2)            pads w=1e30
//   [780,1560)  rec4  (x,y,z,|t|^2+BIAS)       pads w=1e30
//   [1560,1764) pri4  (biased, subset of rec4)
//   [1764,2542) nrm4  (nx,ny,nz,0)
#define BATCH_F4 2544
// float offsets in ws
#define ACC_OFF (NB * BATCH_F4 * 4)   // acc[16]: 0..7 sums, [15] ticket counter
#define MU_OFF  (ACC_OFF + 16)        // uint [2*NPTS]  rec packed (dist|idx) halves
#define MG_OFF  (MU_OFF + 2 * NPTS)   // float[2*NPTS]  gt raw partial-min halves
#define MP_OFF  (MG_OFF + 2 * NPTS)   // float[NPTS]    prior raw partial-min
// acc slots: 2 chamfer, 3 S_cmap, 4 N_cmap, 5 N_gt, 6 N_cons, 7 S_pen

__device__ __constant__ int c_prior[NPRIOR] = {
  697,698,699,700,712,713,714,715,737,738,739,740,741,743,744,745,746,748,749,750,
  753,754,755,756,757,758,759,760,761,762,763,764,765,766,767,768,
  46,47,48,49,164,165,166,167,194,195,223,237,238,280,281,298,301,317,320,323,
  324,325,326,327,328,329,330,331,332,333,340,341,342,343,344,345,346,347,348,349,
  350,351,352,353,354,355,
  356,357,358,359,375,376,386,387,396,397,402,403,413,429,433,434,435,436,437,438,
  439,440,441,442,443,444,452,453,454,455,456,459,460,461,462,463,464,465,466,467,
  468,469,470,471,484,485,486,496,497,506,507,513,514,524,545,546,547,548,549,550,
  551,552,553,555,563,564,565,566,567,570,572,573,574,575,576,577,578,
  580,581,582,583,600,601,602,614,615,624,625,630,631,641,663,664,665,666,667,668,
  670,672,680,681,682,683,684,686,687,688,689,690,691,692,693,694,695,
  73,96,98,99,772,774,775,777
};

// ---------------- Kernel 0: per-batch target arrays + normals + acc init -----
__global__ __launch_bounds__(256) void k_prep(const float* __restrict__ recon,
                                              const float* __restrict__ gt,
                                              const int* __restrict__ faces,
                                              float4* __restrict__ ws4,
                                              float* __restrict__ acc) {
    int b = blockIdx.x, tid = threadIdx.x;
    if (b == 0 && tid < 16) acc[tid] = 0.0f;   // sums + ticket counter
    __shared__ float4 s_r[NV];
    __shared__ float s_vnx[NV], s_vny[NV], s_vnz[NV];
    const float* rb = recon + (size_t)b * NV * 3;
    const float* gb = gt    + (size_t)b * NV * 3;
    float4* gt4  = ws4 + (size_t)b * BATCH_F4;
    float4* rec4 = gt4 + NVP;
    float4* pri4 = rec4 + NVP;
    float4* nrm4 = pri4 + NPRIOR;
    for (int j = tid; j < NVP; j += 256) {
        if (j < NV) {
            float x = rb[3*j], y = rb[3*j+1], z = rb[3*j+2];
            float4 r = make_float4(x, y, z, x*x + y*y + z*z + BIAS);
            s_r[j] = r; rec4[j] = r;
            x = gb[3*j]; y = gb[3*j+1]; z = gb[3*j+2];
            gt4[j] = make_float4(x, y, z, x*x + y*y + z*z);
            s_vnx[j] = 0.0f; s_vny[j] = 0.0f; s_vnz[j] = 0.0f;
        } else {
            float4 pad = make_float4(0.f, 0.f, 0.f, 1e30f);
            rec4[j] = pad; gt4[j] = pad;
        }
    }
    __syncthreads();
    for (int f = tid; f < NFACE; f += 256) {
        int i0 = faces[3*f], i1 = faces[3*f+1], i2 = faces[3*f+2];
        float4 p0 = s_r[i0], p1 = s_r[i1], p2 = s_r[i2];
        float e1x = p1.x - p0.x, e1y = p1.y - p0.y, e1z = p1.z - p0.z;
        float e2x = p2.x - p0.x, e2y = p2.y - p0.y, e2z = p2.z - p0.z;
        float fx = e1y * e2z - e1z * e2y;
        float fy = e1z * e2x - e1x * e2z;
        float fz = e1x * e2y - e1y * e2x;
        atomicAdd(&s_vnx[i0], fx); atomicAdd(&s_vny[i0], fy); atomicAdd(&s_vnz[i0], fz);
        atomicAdd(&s_vnx[i1], fx); atomicAdd(&s_vny[i1], fy); atomicAdd(&s_vnz[i1], fz);
        atomicAdd(&s_vnx[i2], fx); atomicAdd(&s_vny[i2], fy); atomicAdd(&s_vnz[i2], fz);
    }
    __syncthreads();
    for (int j = tid; j < NV; j += 256) {
        float x = s_vnx[j], y = s_vny[j], z = s_vnz[j];
        float inv = 1.0f / (sqrtf(x*x + y*y + z*z) + 1e-12f);
        nrm4[j] = make_float4(x * inv, y * inv, z * inv, 0.0f);
    }
    for (int k = tid; k < NPRIOR; k += 256) pri4[k] = s_r[c_prior[k]];
}

#define LOAD_PTS(ob)                                                          \
    const float4* ob4 = (const float4*)((ob) + (size_t)tid * 24);             \
    float4 q0 = ob4[0], q1 = ob4[1], q2 = ob4[2],                             \
           q3 = ob4[3], q4 = ob4[4], q5 = ob4[5];                             \
    float px[PPT], py[PPT], pz[PPT];                                          \
    px[0]=q0.x; py[0]=q0.y; pz[0]=q0.z;  px[1]=q0.w; py[1]=q1.x; pz[1]=q1.y;  \
    px[2]=q1.z; py[2]=q1.w; pz[2]=q2.x;  px[3]=q2.y; py[3]=q2.z; pz[3]=q2.w;  \
    px[4]=q3.x; py[4]=q3.y; pz[4]=q3.z;  px[5]=q3.w; py[5]=q4.x; pz[5]=q4.y;  \
    px[6]=q4.z; py[6]=q4.w; pz[6]=q5.x;  px[7]=q5.y; py[7]=q5.z; pz[7]=q5.w;

// ---------------- Fused role kernel ----------------
// [0,512): rec half argmin (+prior in h1)  [512,1024): gt half min  [1024,1152): chamfer
__global__ __launch_bounds__(256) void k_fused(const float* __restrict__ obj,
                                               const float4* __restrict__ ws4,
                                               float* __restrict__ acc,
                                               unsigned int* __restrict__ muH,
                                               float* __restrict__ mgH,
                                               float* __restrict__ mpA) {
    __shared__ float4 s_t[NVP];
    __shared__ float s_red;
    int tid = threadIdx.x;
    int blk = blockIdx.x;

    if (blk < REC_BLOCKS) {
        // ============ REC(half) [+PRIOR in h1] ROLE ============
        int b = blk >> 3, chunk = (blk >> 1) & 3, h = blk & 1;
        int hoff = h ? H1_OFF : 0;
        int nt   = h ? H1_N : H0_N;
        const float4* base = ws4 + (size_t)b * BATCH_F4;
        const float4* rec4v = base + NVP;
        const float4* pri4v = base + 2 * NVP;
        for (int j = tid; j < nt; j += 256) s_t[j] = rec4v[hoff + j];
        if (h) for (int j = tid; j < NPRIOR; j += 256) s_t[PRI_S + j] = pri4v[j];
        __syncthreads();

        const float* ob = obj + ((size_t)b * N1V + (size_t)chunk * 2048) * 3;
        LOAD_PTS(ob)
        float nax[PPT], nay[PPT], naz[PPT];
        unsigned int mu[PPT];
#pragma unroll
        for (int i = 0; i < PPT; ++i) {
            nax[i] = -2.0f * px[i]; nay[i] = -2.0f * py[i]; naz[i] = -2.0f * pz[i];
            mu[i] = 0xFFFFFFFFu;
        }
        int nq = nt >> 2;
        for (int jq = 0; jq < nq; ++jq) {
            int j = 4 * jq;
            float4 t0 = s_t[j], t1 = s_t[j+1], t2 = s_t[j+2], t3 = s_t[j+3];
            unsigned int jj = (unsigned int)(hoff + j);
#pragma unroll
            for (int i = 0; i < PPT; ++i) {
                float d0 = fmaf(nax[i], t0.x, fmaf(nay[i], t0.y, fmaf(naz[i], t0.z, t0.w)));
                float d1 = fmaf(nax[i], t1.x, fmaf(nay[i], t1.y, fmaf(naz[i], t1.z, t1.w)));
                float d2 = fmaf(nax[i], t2.x, fmaf(nay[i], t2.y, fmaf(naz[i], t2.z, t2.w)));
                float d3 = fmaf(nax[i], t3.x, fmaf(nay[i], t3.y, fmaf(naz[i], t3.z, t3.w)));
                unsigned int u0 = (__float_as_uint(d0) & 0xFFFFFC00u) | jj;
                unsigned int u1 = (__float_as_uint(d1) & 0xFFFFFC00u) | (jj+1u);
                unsigned int u2 = (__float_as_uint(d2) & 0xFFFFFC00u) | (jj+2u);
                unsigned int u3 = (__float_as_uint(d3) & 0xFFFFFC00u) | (jj+3u);
                mu[i] = min(min(mu[i], min(u0, u1)), min(u2, u3));
            }
        }
        size_t p = (size_t)b * N1V + (size_t)chunk * 2048 + (size_t)tid * PPT;
        unsigned int* mubase = muH + (size_t)h * NPTS + p;
        *(uint4*)mubase       = make_uint4(mu[0], mu[1], mu[2], mu[3]);
        *(uint4*)(mubase + 4) = make_uint4(mu[4], mu[5], mu[6], mu[7]);

        if (h) {
            float mpri[PPT];
#pragma unroll
            for (int i = 0; i < PPT; ++i) mpri[i] = 3.4e38f;
            for (int jq = 0; jq < NPRIOR / 4; ++jq) {
                int j = PRI_S + 4 * jq;
                float4 t0 = s_t[j], t1 = s_t[j+1], t2 = s_t[j+2], t3 = s_t[j+3];
#pragma unroll
                for (int i = 0; i < PPT; ++i) {
                    float d0 = fmaf(nax[i], t0.x, fmaf(nay[i], t0.y, fmaf(naz[i], t0.z, t0.w)));
                    float d1 = fmaf(nax[i], t1.x, fmaf(nay[i], t1.y, fmaf(naz[i], t1.z, t1.w)));
                    float d2 = fmaf(nax[i], t2.x, fmaf(nay[i], t2.y, fmaf(naz[i], t2.z, t2.w)));
                    float d3 = fmaf(nax[i], t3.x, fmaf(nay[i], t3.y, fmaf(naz[i], t3.z, t3.w)));
                    mpri[i] = fminf(fminf(mpri[i], fminf(d0, d1)), fminf(d2, d3));
                }
            }
            float* mpbase = mpA + p;
            *(float4*)mpbase       = make_float4(mpri[0], mpri[1], mpri[2], mpri[3]);
            *(float4*)(mpbase + 4) = make_float4(mpri[4], mpri[5], mpri[6], mpri[7]);
        }
        return;
    }

    if (blk < REC_BLOCKS + GT_BLOCKS) {
        // ============ GT(half) ROLE ============
        int r = blk - REC_BLOCKS;
        int b = r >> 3, chunk = (r >> 1) & 3, h = r & 1;
        int hoff = h ? H1_OFF : 0;
        int nt   = h ? H1_N : H0_N;
        const float4* gt4v = ws4 + (size_t)b * BATCH_F4;
        for (int j = tid; j < nt; j += 256) s_t[j] = gt4v[hoff + j];
        __syncthreads();

        const float* ob = obj + ((size_t)b * N1V + (size_t)chunk * 2048) * 3;
        LOAD_PTS(ob)
        float nax[PPT], nay[PPT], naz[PPT], mgt[PPT];
#pragma unroll
        for (int i = 0; i < PPT; ++i) {
            nax[i] = -2.0f * px[i]; nay[i] = -2.0f * py[i]; naz[i] = -2.0f * pz[i];
            mgt[i] = 3.4e38f;
        }
        int nq = nt >> 2;
        for (int jq = 0; jq < nq; ++jq) {
            int j = 4 * jq;
            float4 t0 = s_t[j], t1 = s_t[j+1], t2 = s_t[j+2], t3 = s_t[j+3];
#pragma unroll
            for (int i = 0; i < PPT; ++i) {
                float d0 = fmaf(nax[i], t0.x, fmaf(nay[i], t0.y, fmaf(naz[i], t0.z, t0.w)));
                float d1 = fmaf(nax[i], t1.x, fmaf(nay[i], t1.y, fmaf(naz[i], t1.z, t1.w)));
                float d2 = fmaf(nax[i], t2.x, fmaf(nay[i], t2.y, fmaf(naz[i], t2.z, t2.w)));
                float d3 = fmaf(nax[i], t3.x, fmaf(nay[i], t3.y, fmaf(naz[i], t3.z, t3.w)));
                mgt[i] = fminf(fminf(mgt[i], fminf(d0, d1)), fminf(d2, d3));
            }
        }
        size_t p = (size_t)b * N1V + (size_t)chunk * 2048 + (size_t)tid * PPT;
        float* mgbase = mgH + (size_t)h * NPTS + p;
        *(float4*)mgbase       = make_float4(mgt[0], mgt[1], mgt[2], mgt[3]);
        *(float4*)(mgbase + 4) = make_float4(mgt[4], mgt[5], mgt[6], mgt[7]);
        return;
    }

    // ============ CHAMFER ROLE (4 sources/thread, full targets) ============
    {
        int c   = blk - (REC_BLOCKS + GT_BLOCKS);
        int b   = c >> 1;
        int dir = c & 1;           // 0: rec->gt, 1: gt->rec
        const float4* base = ws4 + (size_t)b * BATCH_F4;
        const float4* srcv = dir ? base : (base + NVP);   // gt4 : rec4
        const float4* tgtv = dir ? (base + NVP) : base;   // rec4 : gt4
        for (int j = tid; j < NVP; j += 256) s_t[j] = tgtv[j];
        if (tid == 0) s_red = 0.0f;
        __syncthreads();

        const int CPT = 4;               // 256*4 = 1024 >= 778 sources
        float nax[CPT], nay[CPT], naz[CPT], a2[CPT], m[CPT];
        bool valid[CPT];
#pragma unroll
        for (int k = 0; k < CPT; ++k) {
            int p = tid + 256 * k;
            valid[k] = (p < NV);
            float4 s = srcv[valid[k] ? p : 0];
            nax[k] = -2.0f * s.x; nay[k] = -2.0f * s.y; naz[k] = -2.0f * s.z;
            a2[k] = s.w;                  // one of src/tgt carries +BIAS
            m[k] = 3.4e38f;
        }
        for (int j = 0; j < NVP; j += 4) {
            float4 t0 = s_t[j], t1 = s_t[j+1], t2 = s_t[j+2], t3 = s_t[j+3];
#pragma unroll
            for (int k = 0; k < CPT; ++k) {
                float d0 = fmaf(nax[k], t0.x, fmaf(nay[k], t0.y, fmaf(naz[k], t0.z, t0.w)));
                float d1 = fmaf(nax[k], t1.x, fmaf(nay[k], t1.y, fmaf(naz[k], t1.z, t1.w)));
                float d2 = fmaf(nax[k], t2.x, fmaf(nay[k], t2.y, fmaf(naz[k], t2.z, t2.w)));
                float d3 = fmaf(nax[k], t3.x, fmaf(nay[k], t3.y, fmaf(naz[k], t3.z, t3.w)));
                m[k] = fminf(fminf(m[k], fminf(d0, d1)), fminf(d2, d3));
            }
        }
        float local = 0.0f;
#pragma unroll
        for (int k = 0; k < CPT; ++k)
            if (valid[k]) local += fmaxf(a2[k] + m[k] - BIAS, 0.0f);
        atomicAdd(&s_red, local);
        __syncthreads();
        if (tid == 0) atomicAdd(&acc[2], s_red);
    }
}

// ---------------- Combine + finalize (last-block pattern) ----------------
__global__ __launch_bounds__(256) void k_combine(const float* __restrict__ obj,
                                                 const float4* __restrict__ ws4,
                                                 float* __restrict__ acc,
                                                 const unsigned int* __restrict__ muH,
                                                 const float* __restrict__ mgH,
                                                 const float* __restrict__ mpA,
                                                 const float* __restrict__ mean,
                                                 const float* __restrict__ log_var,
                                                 const float* __restrict__ rp,
                                                 const float* __restrict__ xp,
                                                 float* __restrict__ out) {
    int blk = blockIdx.x, tid = threadIdx.x;
    __shared__ float s_red[5];
    __shared__ unsigned int s_ticket;
    if (tid < 5) s_red[tid] = 0.0f;
    __syncthreads();

    size_t p0 = (size_t)blk * 1024 + (size_t)tid * 4;
    int b = blk >> 3;
    const float4* base  = ws4 + (size_t)b * BATCH_F4;
    const float4* rec4v = base + NVP;
    const float4* nrm4v = base + 2 * NVP + NPRIOR;

    const float4* ob4 = (const float4*)(obj + p0 * 3);
    float4 q0 = ob4[0], q1 = ob4[1], q2 = ob4[2];
    float px[4], py[4], pz[4];
    px[0]=q0.x; py[0]=q0.y; pz[0]=q0.z;
    px[1]=q0.w; py[1]=q1.x; pz[1]=q1.y;
    px[2]=q1.z; py[2]=q1.w; pz[2]=q2.x;
    px[3]=q2.y; py[3]=q2.z; pz[3]=q2.w;
    uint4  u0 = *(const uint4*)(muH + p0);
    uint4  u1 = *(const uint4*)(muH + NPTS + p0);
    float4 g0 = *(const float4*)(mgH + p0);
    float4 g1 = *(const float4*)(mgH + NPTS + p0);
    float4 mp = *(const float4*)(mpA + p0);
    unsigned int mus[4] = {min(u0.x,u1.x), min(u0.y,u1.y), min(u0.z,u1.z), min(u0.w,u1.w)};
    float gs[4] = {fminf(g0.x,g1.x), fminf(g0.y,g1.y), fminf(g0.z,g1.z), fminf(g0.w,g1.w)};
    float mps[4] = {mp.x, mp.y, mp.z, mp.w};

    float lS_cmap = 0.0f, lN_cmap = 0.0f, lN_gt = 0.0f, lN_cons = 0.0f, lS_pen = 0.0f;
#pragma unroll
    for (int i = 0; i < 4; ++i) {
        float a2 = px[i]*px[i] + py[i]*py[i] + pz[i]*pz[i];
        float dgt  = fmaxf(a2 + gs[i], 0.0f);
        float dpri = fmaxf(a2 + (mps[i] - BIAS), 0.0f);
        int j = (int)(mus[i] & 0x3FFu);
        float4 t  = rec4v[j];
        float4 nr = nrm4v[j];
        float dot = fmaf(-2.0f*px[i], t.x, fmaf(-2.0f*py[i], t.y,
                     fmaf(-2.0f*pz[i], t.z, t.w - BIAS)));
        float drec = fmaxf(a2 + dot, 0.0f);
        bool cm = drec < 1e-4f;
        bool rc = sqrtf(drec) < 0.005f;
        bool gc = sqrtf(dgt)  < 0.005f;
        if (cm) { lS_cmap += dpri; lN_cmap += 1.0f; }
        if (gc) { lN_gt += 1.0f; if (rc) lN_cons += 1.0f; }
        float ddot = (t.x - px[i]) * nr.x + (t.y - py[i]) * nr.y + (t.z - pz[i]) * nr.z;
        if (ddot > 0.0f) lS_pen += drec;
    }
    atomicAdd(&s_red[0], lS_cmap);
    atomicAdd(&s_red[1], lN_cmap);
    atomicAdd(&s_red[2], lN_gt);
    atomicAdd(&s_red[3], lN_cons);
    atomicAdd(&s_red[4], lS_pen);
    __syncthreads();
    if (tid < 5) atomicAdd(&acc[3 + tid], s_red[tid]);
    __threadfence();
    if (tid == 0) s_ticket = atomicAdd((unsigned int*)&acc[15], 1u);
    __syncthreads();

    if (s_ticket == CMB_BLOCKS - 1) {
        // last block: param/KLD + final loss
        if (tid < 2) s_red[tid] = 0.0f;
        __syncthreads();
        float s_param = 0.0f, s_kld = 0.0f;
        for (int i = tid; i < NB * NPAR; i += 256) {
            float d = rp[i] - xp[i];
            s_param += d * d;
        }
        for (int i = tid; i < NB * NZ; i += 256) {
            float m = mean[i], lv = log_var[i];
            s_kld += 1.0f + lv - m * m - expf(lv);
        }
        atomicAdd(&s_red[0], s_param);
        atomicAdd(&s_red[1], s_kld);
        __syncthreads();
        if (tid == 0) {
            const float fB = 64.0f;
            float a2v = atomicAdd(&acc[2], 0.0f);
            float a3  = atomicAdd(&acc[3], 0.0f);
            float a4  = atomicAdd(&acc[4], 0.0f);
            float a5  = atomicAdd(&acc[5], 0.0f);
            float a6  = atomicAdd(&acc[6], 0.0f);
            float a7  = atomicAdd(&acc[7], 0.0f);
            float param_loss  = s_red[0] / fB;
            float KLD         = -0.5f * s_red[1] / fB * 10.0f;
            float recon_loss  = a2v / fB;
            float cmap_loss   = 3000.0f * a3 / (fB * a4);
            float consistency = -5.0f * a6 / (a5 + 0.0001f);
            float penetr      = 100.0f * a7 / fB;
            out[0] = (recon_loss + KLD) + 0.1f * param_loss + 1000.0f * cmap_loss
                   + 10.0f * consistency + 10.0f * penetr;
        }
    }
}

extern "C" void kernel_launch(void* const* d_in, const int* in_sizes, int n_in,
                              void* d_out, int out_size, void* d_ws, size_t ws_size,
                              hipStream_t stream) {
    (void)in_sizes; (void)n_in; (void)out_size; (void)ws_size;
    const float* obj     = (const float*)d_in[0];
    const float* recon   = (const float*)d_in[1];
    const float* gt      = (const float*)d_in[2];
    const float* mean    = (const float*)d_in[3];
    const float* log_var = (const float*)d_in[4];
    const float* rp      = (const float*)d_in[5];
    const float* xp      = (const float*)d_in[6];
    const int*   faces   = (const int*)d_in[7];
    float4* ws4 = (float4*)d_ws;
    float* acc  = (float*)d_ws + ACC_OFF;
    unsigned int* muH = (unsigned int*)((float*)d_ws + MU_OFF);
    float* mgH  = (float*)d_ws + MG_OFF;
    float* mpA  = (float*)d_ws + MP_OFF;
    float* out  = (float*)d_out;

    k_prep   <<<NB,           256, 0, stream>>>(recon, gt, faces, ws4, acc);
    k_fused  <<<NROLE_BLOCKS, 256, 0, stream>>>(obj, ws4, acc, muH, mgH, mpA);
    k_combine<<<CMB_BLOCKS,   256, 0, stream>>>(obj, ws4, acc, muH, mgH, mpA,
                                                mean, log_var, rp, xp, out);
}

// Round 11
// 223.350 us; speedup vs baseline: 1.1742x; 1.1742x over previous
//
#include <hip/hip_runtime.h>
#include <math.h>

// Problem constants (from reference setup_inputs)
#define NB     64      // batch
#define N1V    8192    // obj points per batch
#define NPTS   (NB * N1V)
#define NV     778     // recon / gt verts
#define NVP    780     // padded to multiple of 4
#define NQ     195     // target quads
#define SEG1Q  51      // first 51 quads = 204 permuted targets = PRIOR set
#define NFACE  1538
#define NZ     64
#define NPAR   61
#define NPRIOR 204
#define PPT    8       // obj points per thread (rec/gt roles)
#define BIAS   0.0625f // 2|a||t| <= 0.06 < BIAS -> biased rec partials stay >= 0

// k_fused roles
#define REC_BLOCKS 256                 // (batch, chunk-of-2048)
#define GT_BLOCKS  256
#define CH_BLOCKS  128                 // (batch, dir)
#define NROLE_BLOCKS (REC_BLOCKS + GT_BLOCKS + CH_BLOCKS)   // 640
#define CMB_BLOCKS 512

// ws float4 layout per batch (BATCH_F4 float4s):
//   [0,780)     gt4    (x,y,z,|t|^2)  original order, pads w=1e30
//   [780,1560)  rec4p  (x,y,z,|t|^2+BIAS) PERMUTED (prior first), pads w=1e30
//   [1560,2340) nrm4p  (nx,ny,nz,0)   PERMUTED to match rec4p
#define BATCH_F4 2352                  // padded stride
// float offsets in ws
#define ACC_OFF (NB * BATCH_F4 * 4)   // acc[16]: [2..7] sums, [15] ticket
#define MG_OFF  (ACC_OFF + 16)        // float[NPTS] raw gt min (unbiased partial)
#define QR_OFF  (MG_OFF + NPTS)       // uchar[NPTS] winning rec quad
#define QP_OFF  (QR_OFF + NPTS / 4)   // uchar[NPTS] winning prior quad
// acc slots: 2 chamfer, 3 S_cmap, 4 N_cmap, 5 N_gt, 6 N_cons, 7 S_pen

__device__ __constant__ int c_prior[NPRIOR] = {
  697,698,699,700,712,713,714,715,737,738,739,740,741,743,744,745,746,748,749,750,
  753,754,755,756,757,758,759,760,761,762,763,764,765,766,767,768,
  46,47,48,49,164,165,166,167,194,195,223,237,238,280,281,298,301,317,320,323,
  324,325,326,327,328,329,330,331,332,333,340,341,342,343,344,345,346,347,348,349,
  350,351,352,353,354,355,
  356,357,358,359,375,376,386,387,396,397,402,403,413,429,433,434,435,436,437,438,
  439,440,441,442,443,444,452,453,454,455,456,459,460,461,462,463,464,465,466,467,
  468,469,470,471,484,485,486,496,497,506,507,513,514,524,545,546,547,548,549,550,
  551,552,553,555,563,564,565,566,567,570,572,573,574,575,576,577,578,
  580,581,582,583,600,601,602,614,615,624,625,630,631,641,663,664,665,666,667,668,
  670,672,680,681,682,683,684,686,687,688,689,690,691,692,693,694,695,
  73,96,98,99,772,774,775,777
};

// ---------------- Kernel 0: permuted target arrays + normals + acc init ------
__global__ __launch_bounds__(256) void k_prep(const float* __restrict__ recon,
                                              const float* __restrict__ gt,
                                              const int* __restrict__ faces,
                                              float4* __restrict__ ws4,
                                              float* __restrict__ acc) {
    int b = blockIdx.x, tid = threadIdx.x;
    if (b == 0 && tid < 16) acc[tid] = 0.0f;
    __shared__ float4 s_r[NV];
    __shared__ float s_vnx[NV], s_vny[NV], s_vnz[NV];
    __shared__ unsigned int s_bm[25];
    __shared__ unsigned short s_pre[26];
    __shared__ unsigned short s_perm[NV];

    if (tid < 25) s_bm[tid] = 0u;
    __syncthreads();
    if (tid < NPRIOR) {
        int v = c_prior[tid];
        atomicOr(&s_bm[v >> 5], 1u << (v & 31));
    }
    const float* rb = recon + (size_t)b * NV * 3;
    const float* gb = gt    + (size_t)b * NV * 3;
    float4* gt4   = ws4 + (size_t)b * BATCH_F4;
    float4* rec4p = gt4 + NVP;
    float4* nrm4p = rec4p + NVP;
    for (int j = tid; j < NV; j += 256) {
        float x = rb[3*j], y = rb[3*j+1], z = rb[3*j+2];
        s_r[j] = make_float4(x, y, z, x*x + y*y + z*z + BIAS);
        x = gb[3*j]; y = gb[3*j+1]; z = gb[3*j+2];
        gt4[j] = make_float4(x, y, z, x*x + y*y + z*z);
        s_vnx[j] = 0.0f; s_vny[j] = 0.0f; s_vnz[j] = 0.0f;
    }
    if (tid < 2) gt4[NV + tid] = make_float4(0.f, 0.f, 0.f, 1e30f);
    __syncthreads();
    if (tid == 0) {
        unsigned int run = 0;
        for (int w = 0; w < 25; ++w) { s_pre[w] = (unsigned short)run; run += __popc(s_bm[w]); }
        s_pre[25] = (unsigned short)run;
    }
    __syncthreads();
    for (int j = tid; j < NV; j += 256) {
        int w = j >> 5;
        unsigned int below = s_bm[w] & ((1u << (j & 31)) - 1u);
        int rank = s_pre[w] + __popc(below);
        bool member = (s_bm[w] >> (j & 31)) & 1u;
        int pos = member ? rank : (NPRIOR + (j - rank));
        s_perm[pos] = (unsigned short)j;
    }
    for (int f = tid; f < NFACE; f += 256) {
        int i0 = faces[3*f], i1 = faces[3*f+1], i2 = faces[3*f+2];
        float4 p0 = s_r[i0], p1 = s_r[i1], p2 = s_r[i2];
        float e1x = p1.x - p0.x, e1y = p1.y - p0.y, e1z = p1.z - p0.z;
        float e2x = p2.x - p0.x, e2y = p2.y - p0.y, e2z = p2.z - p0.z;
        float fx = e1y * e2z - e1z * e2y;
        float fy = e1z * e2x - e1x * e2z;
        float fz = e1x * e2y - e1y * e2x;
        atomicAdd(&s_vnx[i0], fx); atomicAdd(&s_vny[i0], fy); atomicAdd(&s_vnz[i0], fz);
        atomicAdd(&s_vnx[i1], fx); atomicAdd(&s_vny[i1], fy); atomicAdd(&s_vnz[i1], fz);
        atomicAdd(&s_vnx[i2], fx); atomicAdd(&s_vny[i2], fy); atomicAdd(&s_vnz[i2], fz);
    }
    __syncthreads();
    for (int j = tid; j < NVP; j += 256) {
        if (j < NV) {
            int src = s_perm[j];
            rec4p[j] = s_r[src];
            float x = s_vnx[src], y = s_vny[src], z = s_vnz[src];
            float inv = 1.0f / (sqrtf(x*x + y*y + z*z) + 1e-12f);
            nrm4p[j] = make_float4(x * inv, y * inv, z * inv, 0.0f);
        } else {
            rec4p[j] = make_float4(0.f, 0.f, 0.f, 1e30f);
            nrm4p[j] = make_float4(0.f, 0.f, 1.f, 0.0f);
        }
    }
}

#define LOAD_PTS(ob)                                                          \
    const float4* ob4 = (const float4*)((ob) + (size_t)tid * 24);             \
    float4 q0 = ob4[0], q1 = ob4[1], q2 = ob4[2],                             \
           q3 = ob4[3], q4 = ob4[4], q5 = ob4[5];                             \
    float px[PPT], py[PPT], pz[PPT];                                          \
    px[0]=q0.x; py[0]=q0.y; pz[0]=q0.z;  px[1]=q0.w; py[1]=q1.x; pz[1]=q1.y;  \
    px[2]=q1.z; py[2]=q1.w; pz[2]=q2.x;  px[3]=q2.y; py[3]=q2.z; pz[3]=q2.w;  \
    px[4]=q3.x; py[4]=q3.y; pz[4]=q3.z;  px[5]=q3.w; py[5]=q4.x; pz[5]=q4.y;  \
    px[6]=q4.z; py[6]=q4.w; pz[6]=q5.x;  px[7]=q5.y; py[7]=q5.z; pz[7]=q5.w;

// ---------------- Fused role kernel ----------------
// [0,256): rec quad-argmin (prior = snapshot @ quad 51)
// [256,512): gt plain min   [512,640): chamfer
__global__ __launch_bounds__(256) void k_fused(const float* __restrict__ obj,
                                               const float4* __restrict__ ws4,
                                               float* __restrict__ acc,
                                               float* __restrict__ mgA,
                                               unsigned char* __restrict__ qrA,
                                               unsigned char* __restrict__ qpA) {
    __shared__ float4 s_t[NVP];
    __shared__ float s_red;
    int tid = threadIdx.x;
    int blk = blockIdx.x;

    if (blk < REC_BLOCKS) {
        // ============ REC ROLE: quad argmin, prior snapshot ============
        int b = blk >> 2, chunk = blk & 3;
        const float4* rec4p = ws4 + (size_t)b * BATCH_F4 + NVP;
        for (int j = tid; j < NVP; j += 256) s_t[j] = rec4p[j];
        __syncthreads();

        const float* ob = obj + ((size_t)b * N1V + (size_t)chunk * 2048) * 3;
        LOAD_PTS(ob)
        float nax[PPT], nay[PPT], naz[PPT], m[PPT];
        int q[PPT];
#pragma unroll
        for (int i = 0; i < PPT; ++i) {
            nax[i] = -2.0f * px[i]; nay[i] = -2.0f * py[i]; naz[i] = -2.0f * pz[i];
            m[i] = 3.4e38f; q[i] = 0;
        }
        float mp[PPT]; int qp[PPT];
#pragma unroll 1
        for (int jq = 0; jq < SEG1Q; ++jq) {
            int j = 4 * jq;
            float4 t0 = s_t[j], t1 = s_t[j+1], t2 = s_t[j+2], t3 = s_t[j+3];
#pragma unroll
            for (int i = 0; i < PPT; ++i) {
                float d0 = fmaf(nax[i], t0.x, fmaf(nay[i], t0.y, fmaf(naz[i], t0.z, t0.w)));
                float d1 = fmaf(nax[i], t1.x, fmaf(nay[i], t1.y, fmaf(naz[i], t1.z, t1.w)));
                float d2 = fmaf(nax[i], t2.x, fmaf(nay[i], t2.y, fmaf(naz[i], t2.z, t2.w)));
                float d3 = fmaf(nax[i], t3.x, fmaf(nay[i], t3.y, fmaf(naz[i], t3.z, t3.w)));
                float mn = fminf(fminf(fminf(d0, d1), fminf(d2, d3)), m[i]);
                q[i] = (mn < m[i]) ? jq : q[i];
                m[i] = mn;
            }
        }
#pragma unroll
        for (int i = 0; i < PPT; ++i) { mp[i] = m[i]; qp[i] = q[i]; }
#pragma unroll 1
        for (int jq = SEG1Q; jq < NQ; ++jq) {
            int j = 4 * jq;
            float4 t0 = s_t[j], t1 = s_t[j+1], t2 = s_t[j+2], t3 = s_t[j+3];
#pragma unroll
            for (int i = 0; i < PPT; ++i) {
                float d0 = fmaf(nax[i], t0.x, fmaf(nay[i], t0.y, fmaf(naz[i], t0.z, t0.w)));
                float d1 = fmaf(nax[i], t1.x, fmaf(nay[i], t1.y, fmaf(naz[i], t1.z, t1.w)));
                float d2 = fmaf(nax[i], t2.x, fmaf(nay[i], t2.y, fmaf(naz[i], t2.z, t2.w)));
                float d3 = fmaf(nax[i], t3.x, fmaf(nay[i], t3.y, fmaf(naz[i], t3.z, t3.w)));
                float mn = fminf(fminf(fminf(d0, d1), fminf(d2, d3)), m[i]);
                q[i] = (mn < m[i]) ? jq : q[i];
                m[i] = mn;
            }
        }
        (void)mp;
        size_t p = (size_t)b * N1V + (size_t)chunk * 2048 + (size_t)tid * PPT;
        unsigned int r0 = (unsigned)q[0] | ((unsigned)q[1] << 8) |
                          ((unsigned)q[2] << 16) | ((unsigned)q[3] << 24);
        unsigned int r1 = (unsigned)q[4] | ((unsigned)q[5] << 8) |
                          ((unsigned)q[6] << 16) | ((unsigned)q[7] << 24);
        unsigned int p0u = (unsigned)qp[0] | ((unsigned)qp[1] << 8) |
                           ((unsigned)qp[2] << 16) | ((unsigned)qp[3] << 24);
        unsigned int p1u = (unsigned)qp[4] | ((unsigned)qp[5] << 8) |
                           ((unsigned)qp[6] << 16) | ((unsigned)qp[7] << 24);
        *(uint2*)(qrA + p) = make_uint2(r0, r1);
        *(uint2*)(qpA + p) = make_uint2(p0u, p1u);
        return;
    }

    if (blk < REC_BLOCKS + GT_BLOCKS) {
        // ============ GT ROLE: plain min, store raw partial ============
        int r = blk - REC_BLOCKS;
        int b = r >> 2, chunk = r & 3;
        const float4* gt4v = ws4 + (size_t)b * BATCH_F4;
        for (int j = tid; j < NVP; j += 256) s_t[j] = gt4v[j];
        __syncthreads();

        const float* ob = obj + ((size_t)b * N1V + (size_t)chunk * 2048) * 3;
        LOAD_PTS(ob)
        float nax[PPT], nay[PPT], naz[PPT], mgt[PPT];
#pragma unroll
        for (int i = 0; i < PPT; ++i) {
            nax[i] = -2.0f * px[i]; nay[i] = -2.0f * py[i]; naz[i] = -2.0f * pz[i];
            mgt[i] = 3.4e38f;
        }
#pragma unroll 1
        for (int jq = 0; jq < NQ; ++jq) {
            int j = 4 * jq;
            float4 t0 = s_t[j], t1 = s_t[j+1], t2 = s_t[j+2], t3 = s_t[j+3];
#pragma unroll
            for (int i = 0; i < PPT; ++i) {
                float d0 = fmaf(nax[i], t0.x, fmaf(nay[i], t0.y, fmaf(naz[i], t0.z, t0.w)));
                float d1 = fmaf(nax[i], t1.x, fmaf(nay[i], t1.y, fmaf(naz[i], t1.z, t1.w)));
                float d2 = fmaf(nax[i], t2.x, fmaf(nay[i], t2.y, fmaf(naz[i], t2.z, t2.w)));
                float d3 = fmaf(nax[i], t3.x, fmaf(nay[i], t3.y, fmaf(naz[i], t3.z, t3.w)));
                mgt[i] = fminf(fminf(mgt[i], fminf(d0, d1)), fminf(d2, d3));
            }
        }
        size_t p = (size_t)b * N1V + (size_t)chunk * 2048 + (size_t)tid * PPT;
        *(float4*)(mgA + p)     = make_float4(mgt[0], mgt[1], mgt[2], mgt[3]);
        *(float4*)(mgA + p + 4) = make_float4(mgt[4], mgt[5], mgt[6], mgt[7]);
        return;
    }

    // ============ CHAMFER ROLE (4 sources/thread) ============
    {
        int c   = blk - (REC_BLOCKS + GT_BLOCKS);
        int b   = c >> 1;
        int dir = c & 1;           // 0: rec->gt, 1: gt->rec
        const float4* base = ws4 + (size_t)b * BATCH_F4;
        const float4* srcv = dir ? base : (base + NVP);   // gt4 : rec4p
        const float4* tgtv = dir ? (base + NVP) : base;   // rec4p : gt4
        for (int j = tid; j < NVP; j += 256) s_t[j] = tgtv[j];
        if (tid == 0) s_red = 0.0f;
        __syncthreads();

        const int CPT = 4;
        float nax[CPT], nay[CPT], naz[CPT], a2[CPT], m[CPT];
        bool valid[CPT];
#pragma unroll
        for (int k = 0; k < CPT; ++k) {
            int p = tid + 256 * k;
            valid[k] = (p < NV);
            float4 s = srcv[valid[k] ? p : 0];
            nax[k] = -2.0f * s.x; nay[k] = -2.0f * s.y; naz[k] = -2.0f * s.z;
            a2[k] = s.w;                  // one of src/tgt carries +BIAS
            m[k] = 3.4e38f;
        }
#pragma unroll 1
        for (int j = 0; j < NVP; j += 4) {
            float4 t0 = s_t[j], t1 = s_t[j+1], t2 = s_t[j+2], t3 = s_t[j+3];
#pragma unroll
            for (int k = 0; k < CPT; ++k) {
                float d0 = fmaf(nax[k], t0.x, fmaf(nay[k], t0.y, fmaf(naz[k], t0.z, t0.w)));
                float d1 = fmaf(nax[k], t1.x, fmaf(nay[k], t1.y, fmaf(naz[k], t1.z, t1.w)));
                float d2 = fmaf(nax[k], t2.x, fmaf(nay[k], t2.y, fmaf(naz[k], t2.z, t2.w)));
                float d3 = fmaf(nax[k], t3.x, fmaf(nay[k], t3.y, fmaf(naz[k], t3.z, t3.w)));
                m[k] = fminf(fminf(m[k], fminf(d0, d1)), fminf(d2, d3));
            }
        }
        float local = 0.0f;
#pragma unroll
        for (int k = 0; k < CPT; ++k)
            if (valid[k]) local += fmaxf(a2[k] + m[k] - BIAS, 0.0f);
        atomicAdd(&s_red, local);
        __syncthreads();
        if (tid == 0) atomicAdd(&acc[2], s_red);
    }
}

// ---------------- Combine + finalize (ticket) ----------------
__global__ __launch_bounds__(256) void k_combine(const float* __restrict__ obj,
                                                 const float4* __restrict__ ws4,
                                                 float* __restrict__ acc,
                                                 const float* __restrict__ mgA,
                                                 const unsigned char* __restrict__ qrA,
                                                 const unsigned char* __restrict__ qpA,
                                                 const float* __restrict__ mean,
                                                 const float* __restrict__ log_var,
                                                 const float* __restrict__ rp,
                                                 const float* __restrict__ xp,
                                                 float* __restrict__ out) {
    int blk = blockIdx.x, tid = threadIdx.x;
    __shared__ float s_red[5];
    __shared__ unsigned int s_ticket;
    if (tid < 5) s_red[tid] = 0.0f;
    __syncthreads();

    size_t p0 = (size_t)blk * 1024 + (size_t)tid * 4;
    int b = blk >> 3;
    const float4* base  = ws4 + (size_t)b * BATCH_F4;
    const float4* rec4p = base + NVP;
    const float4* nrm4p = base + 2 * NVP;

    const float4* ob4 = (const float4*)(obj + p0 * 3);
    float4 o0 = ob4[0], o1 = ob4[1], o2 = ob4[2];
    float px[4], py[4], pz[4];
    px[0]=o0.x; py[0]=o0.y; pz[0]=o0.z;
    px[1]=o0.w; py[1]=o1.x; pz[1]=o1.y;
    px[2]=o1.z; py[2]=o1.w; pz[2]=o2.x;
    px[3]=o2.y; py[3]=o2.z; pz[3]=o2.w;
    float4 mg4 = *(const float4*)(mgA + p0);
    unsigned int qr = *(const unsigned int*)(qrA + p0);
    unsigned int qq = *(const unsigned int*)(qpA + p0);
    float mgs[4] = {mg4.x, mg4.y, mg4.z, mg4.w};

    float lS_cmap = 0.0f, lN_cmap = 0.0f, lN_gt = 0.0f, lN_cons = 0.0f, lS_pen = 0.0f;
#pragma unroll
    for (int i = 0; i < 4; ++i) {
        float a2  = px[i]*px[i] + py[i]*py[i] + pz[i]*pz[i];
        float nax = -2.0f * px[i], nay = -2.0f * py[i], naz = -2.0f * pz[i];
        // rec winning-quad re-eval (bit-identical fma chain)
        int jr = 4 * (int)((qr >> (8 * i)) & 0xFFu);
        float4 t0 = rec4p[jr], t1 = rec4p[jr+1], t2 = rec4p[jr+2], t3 = rec4p[jr+3];
        float d0 = fmaf(nax, t0.x, fmaf(nay, t0.y, fmaf(naz, t0.z, t0.w)));
        float d1 = fmaf(nax, t1.x, fmaf(nay, t1.y, fmaf(naz, t1.z, t1.w)));
        float d2 = fmaf(nax, t2.x, fmaf(nay, t2.y, fmaf(naz, t2.z, t2.w)));
        float d3 = fmaf(nax, t3.x, fmaf(nay, t3.y, fmaf(naz, t3.z, t3.w)));
        float mmin = fminf(fminf(d0, d1), fminf(d2, d3));
        int off = (d0 == mmin) ? 0 : ((d1 == mmin) ? 1 : ((d2 == mmin) ? 2 : 3));
        int jstar = jr + off;
        float drec = fmaxf(a2 + (mmin - BIAS), 0.0f);
        // prior winning-quad re-eval (value only)
        int jp = 4 * (int)((qq >> (8 * i)) & 0xFFu);
        float4 u0 = rec4p[jp], u1 = rec4p[jp+1], u2 = rec4p[jp+2], u3 = rec4p[jp+3];
        float e0 = fmaf(nax, u0.x, fmaf(nay, u0.y, fmaf(naz, u0.z, u0.w)));
        float e1 = fmaf(nax, u1.x, fmaf(nay, u1.y, fmaf(naz, u1.z, u1.w)));
        float e2 = fmaf(nax, u2.x, fmaf(nay, u2.y, fmaf(naz, u2.z, u2.w)));
        float e3 = fmaf(nax, u3.x, fmaf(nay, u3.y, fmaf(naz, u3.z, u3.w)));
        float pmin = fminf(fminf(e0, e1), fminf(e2, e3));
        float dpri = fmaxf(a2 + (pmin - BIAS), 0.0f);
        float dgt  = fmaxf(a2 + mgs[i], 0.0f);
        bool cm = drec < 1e-4f;
        bool rc = sqrtf(drec) < 0.005f;
        bool gc = sqrtf(dgt)  < 0.005f;
        if (cm) { lS_cmap += dpri; lN_cmap += 1.0f; }
        if (gc) { lN_gt += 1.0f; if (rc) lN_cons += 1.0f; }
        float4 tS = rec4p[jstar];
        float4 nr = nrm4p[jstar];
        float ddot = (tS.x - px[i]) * nr.x + (tS.y - py[i]) * nr.y + (tS.z - pz[i]) * nr.z;
        if (ddot > 0.0f) lS_pen += drec;
    }
    atomicAdd(&s_red[0], lS_cmap);
    atomicAdd(&s_red[1], lN_cmap);
    atomicAdd(&s_red[2], lN_gt);
    atomicAdd(&s_red[3], lN_cons);
    atomicAdd(&s_red[4], lS_pen);
    __syncthreads();
    if (tid < 5) atomicAdd(&acc[3 + tid], s_red[tid]);
    __threadfence();
    if (tid == 0) s_ticket = atomicAdd((unsigned int*)&acc[15], 1u);
    __syncthreads();

    if (s_ticket == CMB_BLOCKS - 1) {
        if (tid < 2) s_red[tid] = 0.0f;
        __syncthreads();
        float s_param = 0.0f, s_kld = 0.0f;
        for (int i = tid; i < NB * NPAR; i += 256) {
            float d = rp[i] - xp[i];
            s_param += d * d;
        }
        for (int i = tid; i < NB * NZ; i += 256) {
            float m = mean[i], lv = log_var[i];
            s_kld += 1.0f + lv - m * m - expf(lv);
        }
        atomicAdd(&s_red[0], s_param);
        atomicAdd(&s_red[1], s_kld);
        __syncthreads();
        if (tid == 0) {
            const float fB = 64.0f;
            float a2v = atomicAdd(&acc[2], 0.0f);
            float a3  = atomicAdd(&acc[3], 0.0f);
            float a4  = atomicAdd(&acc[4], 0.0f);
            float a5  = atomicAdd(&acc[5], 0.0f);
            float a6  = atomicAdd(&acc[6], 0.0f);
            float a7  = atomicAdd(&acc[7], 0.0f);
            float param_loss  = s_red[0] / fB;
            float KLD         = -0.5f * s_red[1] / fB * 10.0f;
            float recon_loss  = a2v / fB;
            float cmap_loss   = 3000.0f * a3 / (fB * a4);
            float consistency = -5.0f * a6 / (a5 + 0.0001f);
            float penetr      = 100.0f * a7 / fB;
            out[0] = (recon_loss + KLD) + 0.1f * param_loss + 1000.0f * cmap_loss
                   + 10.0f * consistency + 10.0f * penetr;
        }
    }
}

extern "C" void kernel_launch(void* const* d_in, const int* in_sizes, int n_in,
                              void* d_out, int out_size, void* d_ws, size_t ws_size,
                              hipStream_t stream) {
    (void)in_sizes; (void)n_in; (void)out_size; (void)ws_size;
    const float* obj     = (const float*)d_in[0];
    const float* recon   = (const float*)d_in[1];
    const float* gt      = (const float*)d_in[2];
    const float* mean    = (const float*)d_in[3];
    const float* log_var = (const float*)d_in[4];
    const float* rp      = (const float*)d_in[5];
    const float* xp      = (const float*)d_in[6];
    const int*   faces   = (const int*)d_in[7];
    float4* ws4 = (float4*)d_ws;
    float* acc  = (float*)d_ws + ACC_OFF;
    float* mgA  = (float*)d_ws + MG_OFF;
    unsigned char* qrA = (unsigned char*)((float*)d_ws + QR_OFF);
    unsigned char* qpA = (unsigned char*)((float*)d_ws + QP_OFF);
    float* out  = (float*)d_out;

    k_prep   <<<NB,           256, 0, stream>>>(recon, gt, faces, ws4, acc);
    k_fused  <<<NROLE_BLOCKS, 256, 0, stream>>>(obj, ws4, acc, mgA, qrA, qpA);
    k_combine<<<CMB_BLOCKS,   256, 0, stream>>>(obj, ws4, acc, mgA, qrA, qpA,
                                                mean, log_var, rp, xp, out);
}

// Round 12
// 197.402 us; speedup vs baseline: 1.3286x; 1.1314x over previous
//
#include <hip/hip_runtime.h>
#include <math.h>

// Problem constants (from reference setup_inputs)
#define NB     64      // batch
#define N1V    8192    // obj points per batch
#define NPTS   (NB * N1V)
#define NV     778     // recon / gt verts
#define NVP    780     // padded to multiple of 4
#define NQ     195     // target quads
#define SEG1Q  51      // first 51 quads = 204 permuted targets = PRIOR set
#define NFACE  1538
#define NZ     64
#define NPAR   61
#define NPRIOR 204
#define PPT    8       // obj points per thread (rec/gt roles)
#define BIAS   0.0625f // 2|a||t| <= 0.06 < BIAS -> biased rec partials stay >= 0

// k_fused roles
#define REC_BLOCKS 256                 // (batch, chunk-of-2048)
#define GT_BLOCKS  256
#define CH_BLOCKS  128                 // (batch, dir)
#define NROLE_BLOCKS (REC_BLOCKS + GT_BLOCKS + CH_BLOCKS)   // 640
#define CMB_BLOCKS 64                  // 64*256 uints = NPTS/8 bytes... (4B each)

// ws float4 layout per batch (BATCH_F4 float4s):
//   [0,780)     gt4    (x,y,z,|t|^2)  original order, pads w=1e30
//   [780,1560)  rec4p  (x,y,z,|t|^2+BIAS) PERMUTED (prior first), pads w=1e30
//   [1560,2340) nrm4p  (nx,ny,nz,0)   PERMUTED to match rec4p
#define BATCH_F4 2352                  // padded stride
// float offsets in ws
#define ACC_OFF (NB * BATCH_F4 * 4)   // acc[16]: [2..7] sums, [15] ticket
#define RC_OFF  (ACC_OFF + 16)        // uchar[NPTS/8] rec-cmap bits (1/pt)
#define GC_OFF  (RC_OFF + NPTS / 32)  // uchar[NPTS/8] gt-cmap bits
// acc slots: 2 chamfer, 3 S_cmap, 4 N_cmap, 5 N_gt, 6 N_cons, 7 S_pen

__device__ __constant__ int c_prior[NPRIOR] = {
  697,698,699,700,712,713,714,715,737,738,739,740,741,743,744,745,746,748,749,750,
  753,754,755,756,757,758,759,760,761,762,763,764,765,766,767,768,
  46,47,48,49,164,165,166,167,194,195,223,237,238,280,281,298,301,317,320,323,
  324,325,326,327,328,329,330,331,332,333,340,341,342,343,344,345,346,347,348,349,
  350,351,352,353,354,355,
  356,357,358,359,375,376,386,387,396,397,402,403,413,429,433,434,435,436,437,438,
  439,440,441,442,443,444,452,453,454,455,456,459,460,461,462,463,464,465,466,467,
  468,469,470,471,484,485,486,496,497,506,507,513,514,524,545,546,547,548,549,550,
  551,552,553,555,563,564,565,566,567,570,572,573,574,575,576,577,578,
  580,581,582,583,600,601,602,614,615,624,625,630,631,641,663,664,665,666,667,668,
  670,672,680,681,682,683,684,686,687,688,689,690,691,692,693,694,695,
  73,96,98,99,772,774,775,777
};

// ---------------- Kernel 0: permuted target arrays + normals + acc init ------
__global__ __launch_bounds__(256) void k_prep(const float* __restrict__ recon,
                                              const float* __restrict__ gt,
                                              const int* __restrict__ faces,
                                              float4* __restrict__ ws4,
                                              float* __restrict__ acc) {
    int b = blockIdx.x, tid = threadIdx.x;
    if (b == 0 && tid < 16) acc[tid] = 0.0f;
    __shared__ float4 s_r[NV];
    __shared__ float s_vnx[NV], s_vny[NV], s_vnz[NV];
    __shared__ unsigned int s_bm[25];
    __shared__ unsigned short s_pre[26];
    __shared__ unsigned short s_perm[NV];

    if (tid < 25) s_bm[tid] = 0u;
    __syncthreads();
    if (tid < NPRIOR) {
        int v = c_prior[tid];
        atomicOr(&s_bm[v >> 5], 1u << (v & 31));
    }
    const float* rb = recon + (size_t)b * NV * 3;
    const float* gb = gt    + (size_t)b * NV * 3;
    float4* gt4   = ws4 + (size_t)b * BATCH_F4;
    float4* rec4p = gt4 + NVP;
    float4* nrm4p = rec4p + NVP;
    for (int j = tid; j < NV; j += 256) {
        float x = rb[3*j], y = rb[3*j+1], z = rb[3*j+2];
        s_r[j] = make_float4(x, y, z, x*x + y*y + z*z + BIAS);
        x = gb[3*j]; y = gb[3*j+1]; z = gb[3*j+2];
        gt4[j] = make_float4(x, y, z, x*x + y*y + z*z);
        s_vnx[j] = 0.0f; s_vny[j] = 0.0f; s_vnz[j] = 0.0f;
    }
    if (tid < 2) gt4[NV + tid] = make_float4(0.f, 0.f, 0.f, 1e30f);
    __syncthreads();
    if (tid == 0) {
        unsigned int run = 0;
        for (int w = 0; w < 25; ++w) { s_pre[w] = (unsigned short)run; run += __popc(s_bm[w]); }
        s_pre[25] = (unsigned short)run;
    }
    __syncthreads();
    for (int j = tid; j < NV; j += 256) {
        int w = j >> 5;
        unsigned int below = s_bm[w] & ((1u << (j & 31)) - 1u);
        int rank = s_pre[w] + __popc(below);
        bool member = (s_bm[w] >> (j & 31)) & 1u;
        int pos = member ? rank : (NPRIOR + (j - rank));
        s_perm[pos] = (unsigned short)j;
    }
    for (int f = tid; f < NFACE; f += 256) {
        int i0 = faces[3*f], i1 = faces[3*f+1], i2 = faces[3*f+2];
        float4 p0 = s_r[i0], p1 = s_r[i1], p2 = s_r[i2];
        float e1x = p1.x - p0.x, e1y = p1.y - p0.y, e1z = p1.z - p0.z;
        float e2x = p2.x - p0.x, e2y = p2.y - p0.y, e2z = p2.z - p0.z;
        float fx = e1y * e2z - e1z * e2y;
        float fy = e1z * e2x - e1x * e2z;
        float fz = e1x * e2y - e1y * e2x;
        atomicAdd(&s_vnx[i0], fx); atomicAdd(&s_vny[i0], fy); atomicAdd(&s_vnz[i0], fz);
        atomicAdd(&s_vnx[i1], fx); atomicAdd(&s_vny[i1], fy); atomicAdd(&s_vnz[i1], fz);
        atomicAdd(&s_vnx[i2], fx); atomicAdd(&s_vny[i2], fy); atomicAdd(&s_vnz[i2], fz);
    }
    __syncthreads();
    for (int j = tid; j < NVP; j += 256) {
        if (j < NV) {
            int src = s_perm[j];
            rec4p[j] = s_r[src];
            float x = s_vnx[src], y = s_vny[src], z = s_vnz[src];
            float inv = 1.0f / (sqrtf(x*x + y*y + z*z) + 1e-12f);
            nrm4p[j] = make_float4(x * inv, y * inv, z * inv, 0.0f);
        } else {
            rec4p[j] = make_float4(0.f, 0.f, 0.f, 1e30f);
            nrm4p[j] = make_float4(0.f, 0.f, 1.f, 0.0f);
        }
    }
}

#define LOAD_PTS(ob)                                                          \
    const float4* ob4 = (const float4*)((ob) + (size_t)tid * 24);             \
    float4 q0 = ob4[0], q1 = ob4[1], q2 = ob4[2],                             \
           q3 = ob4[3], q4 = ob4[4], q5 = ob4[5];                             \
    float px[PPT], py[PPT], pz[PPT];                                          \
    px[0]=q0.x; py[0]=q0.y; pz[0]=q0.z;  px[1]=q0.w; py[1]=q1.x; pz[1]=q1.y;  \
    px[2]=q1.z; py[2]=q1.w; pz[2]=q2.x;  px[3]=q2.y; py[3]=q2.z; pz[3]=q2.w;  \
    px[4]=q3.x; py[4]=q3.y; pz[4]=q3.z;  px[5]=q3.w; py[5]=q4.x; pz[5]=q4.y;  \
    px[6]=q4.z; py[6]=q4.w; pz[6]=q5.x;  px[7]=q5.y; py[7]=q5.z; pz[7]=q5.w;

// ---------------- Fused role kernel ----------------
// [0,256): rec quad-argmin + full epilogue  [256,512): gt min + gc bits
// [512,640): chamfer
__global__ __launch_bounds__(256) void k_fused(const float* __restrict__ obj,
                                               const float4* __restrict__ ws4,
                                               float* __restrict__ acc,
                                               unsigned char* __restrict__ rcA,
                                               unsigned char* __restrict__ gcA) {
    __shared__ float4 s_t[NVP];
    __shared__ float s_red[3];
    int tid = threadIdx.x;
    int blk = blockIdx.x;

    if (blk < REC_BLOCKS) {
        // ============ REC ROLE: scan + inline epilogue ============
        int b = blk >> 2, chunk = blk & 3;
        const float4* base = ws4 + (size_t)b * BATCH_F4;
        const float4* rec4p = base + NVP;
        const float4* nrm4p = base + 2 * NVP;
        for (int j = tid; j < NVP; j += 256) s_t[j] = rec4p[j];
        if (tid < 3) s_red[tid] = 0.0f;
        __syncthreads();

        const float* ob = obj + ((size_t)b * N1V + (size_t)chunk * 2048) * 3;
        LOAD_PTS(ob)
        float nax[PPT], nay[PPT], naz[PPT], m[PPT];
        int q[PPT];
#pragma unroll
        for (int i = 0; i < PPT; ++i) {
            nax[i] = -2.0f * px[i]; nay[i] = -2.0f * py[i]; naz[i] = -2.0f * pz[i];
            m[i] = 3.4e38f; q[i] = 0;
        }
        float mp[PPT];
#pragma unroll 1
        for (int jq = 0; jq < SEG1Q; ++jq) {
            int j = 4 * jq;
            float4 t0 = s_t[j], t1 = s_t[j+1], t2 = s_t[j+2], t3 = s_t[j+3];
#pragma unroll
            for (int i = 0; i < PPT; ++i) {
                float d0 = fmaf(nax[i], t0.x, fmaf(nay[i], t0.y, fmaf(naz[i], t0.z, t0.w)));
                float d1 = fmaf(nax[i], t1.x, fmaf(nay[i], t1.y, fmaf(naz[i], t1.z, t1.w)));
                float d2 = fmaf(nax[i], t2.x, fmaf(nay[i], t2.y, fmaf(naz[i], t2.z, t2.w)));
                float d3 = fmaf(nax[i], t3.x, fmaf(nay[i], t3.y, fmaf(naz[i], t3.z, t3.w)));
                float mn = fminf(fminf(fminf(d0, d1), fminf(d2, d3)), m[i]);
                q[i] = (mn < m[i]) ? jq : q[i];
                m[i] = mn;
            }
        }
#pragma unroll
        for (int i = 0; i < PPT; ++i) mp[i] = m[i];   // prior min snapshot
#pragma unroll 1
        for (int jq = SEG1Q; jq < NQ; ++jq) {
            int j = 4 * jq;
            float4 t0 = s_t[j], t1 = s_t[j+1], t2 = s_t[j+2], t3 = s_t[j+3];
#pragma unroll
            for (int i = 0; i < PPT; ++i) {
                float d0 = fmaf(nax[i], t0.x, fmaf(nay[i], t0.y, fmaf(naz[i], t0.z, t0.w)));
                float d1 = fmaf(nax[i], t1.x, fmaf(nay[i], t1.y, fmaf(naz[i], t1.z, t1.w)));
                float d2 = fmaf(nax[i], t2.x, fmaf(nay[i], t2.y, fmaf(naz[i], t2.z, t2.w)));
                float d3 = fmaf(nax[i], t3.x, fmaf(nay[i], t3.y, fmaf(naz[i], t3.z, t3.w)));
                float mn = fminf(fminf(fminf(d0, d1), fminf(d2, d3)), m[i]);
                q[i] = (mn < m[i]) ? jq : q[i];
                m[i] = mn;
            }
        }
        // ---- inline epilogue ----
        float lS_cmap = 0.0f, lN_cmap = 0.0f, lS_pen = 0.0f;
        unsigned int rcbits = 0;
#pragma unroll
        for (int i = 0; i < PPT; ++i) {
            float a2 = px[i]*px[i] + py[i]*py[i] + pz[i]*pz[i];
            float drec = fmaxf(a2 + (m[i]  - BIAS), 0.0f);
            float dpri = fmaxf(a2 + (mp[i] - BIAS), 0.0f);
            bool cm = drec < 1e-4f;
            bool rc = sqrtf(drec) < 0.005f;
            if (cm) { lS_cmap += dpri; lN_cmap += 1.0f; }
            if (rc) rcbits |= (1u << i);
            // winning-quad re-eval from LDS for jstar (bit-identical fma chain)
            int jr = 4 * q[i];
            float4 t0 = s_t[jr], t1 = s_t[jr+1], t2 = s_t[jr+2], t3 = s_t[jr+3];
            float d0 = fmaf(nax[i], t0.x, fmaf(nay[i], t0.y, fmaf(naz[i], t0.z, t0.w)));
            float d1 = fmaf(nax[i], t1.x, fmaf(nay[i], t1.y, fmaf(naz[i], t1.z, t1.w)));
            float d2 = fmaf(nax[i], t2.x, fmaf(nay[i], t2.y, fmaf(naz[i], t2.z, t2.w)));
            float d3 = fmaf(nax[i], t3.x, fmaf(nay[i], t3.y, fmaf(naz[i], t3.z, t3.w)));
            float mmin = fminf(fminf(d0, d1), fminf(d2, d3));
            int off = (d0 == mmin) ? 0 : ((d1 == mmin) ? 1 : ((d2 == mmin) ? 2 : 3));
            int jstar = jr + off;
            float4 tS = s_t[jstar];
            float4 nr = nrm4p[jstar];
            float ddot = (tS.x - px[i]) * nr.x + (tS.y - py[i]) * nr.y
                       + (tS.z - pz[i]) * nr.z;
            if (ddot > 0.0f) lS_pen += drec;
        }
        rcA[(size_t)blk * 256 + tid] = (unsigned char)rcbits;
        atomicAdd(&s_red[0], lS_cmap);
        atomicAdd(&s_red[1], lN_cmap);
        atomicAdd(&s_red[2], lS_pen);
        __syncthreads();
        if (tid == 0) atomicAdd(&acc[3], s_red[0]);
        if (tid == 1) atomicAdd(&acc[4], s_red[1]);
        if (tid == 2) atomicAdd(&acc[7], s_red[2]);
        return;
    }

    if (blk < REC_BLOCKS + GT_BLOCKS) {
        // ============ GT ROLE: min scan + gc bits ============
        int r = blk - REC_BLOCKS;
        int b = r >> 2, chunk = r & 3;
        const float4* gt4v = ws4 + (size_t)b * BATCH_F4;
        for (int j = tid; j < NVP; j += 256) s_t[j] = gt4v[j];
        if (tid == 0) s_red[0] = 0.0f;
        __syncthreads();

        const float* ob = obj + ((size_t)b * N1V + (size_t)chunk * 2048) * 3;
        LOAD_PTS(ob)
        float nax[PPT], nay[PPT], naz[PPT], mgt[PPT];
#pragma unroll
        for (int i = 0; i < PPT; ++i) {
            nax[i] = -2.0f * px[i]; nay[i] = -2.0f * py[i]; naz[i] = -2.0f * pz[i];
            mgt[i] = 3.4e38f;
        }
#pragma unroll 1
        for (int jq = 0; jq < NQ; ++jq) {
            int j = 4 * jq;
            float4 t0 = s_t[j], t1 = s_t[j+1], t2 = s_t[j+2], t3 = s_t[j+3];
#pragma unroll
            for (int i = 0; i < PPT; ++i) {
                float d0 = fmaf(nax[i], t0.x, fmaf(nay[i], t0.y, fmaf(naz[i], t0.z, t0.w)));
                float d1 = fmaf(nax[i], t1.x, fmaf(nay[i], t1.y, fmaf(naz[i], t1.z, t1.w)));
                float d2 = fmaf(nax[i], t2.x, fmaf(nay[i], t2.y, fmaf(naz[i], t2.z, t2.w)));
                float d3 = fmaf(nax[i], t3.x, fmaf(nay[i], t3.y, fmaf(naz[i], t3.z, t3.w)));
                mgt[i] = fminf(fminf(mgt[i], fminf(d0, d1)), fminf(d2, d3));
            }
        }
        float lN_gt = 0.0f;
        unsigned int gcbits = 0;
#pragma unroll
        for (int i = 0; i < PPT; ++i) {
            float a2 = px[i]*px[i] + py[i]*py[i] + pz[i]*pz[i];
            float dgt = fmaxf(a2 + mgt[i], 0.0f);
            if (sqrtf(dgt) < 0.005f) { lN_gt += 1.0f; gcbits |= (1u << i); }
        }
        gcA[(size_t)r * 256 + tid] = (unsigned char)gcbits;
        atomicAdd(&s_red[0], lN_gt);
        __syncthreads();
        if (tid == 0) atomicAdd(&acc[5], s_red[0]);
        return;
    }

    // ============ CHAMFER ROLE (4 sources/thread) ============
    {
        int c   = blk - (REC_BLOCKS + GT_BLOCKS);
        int b   = c >> 1;
        int dir = c & 1;           // 0: rec->gt, 1: gt->rec
        const float4* base = ws4 + (size_t)b * BATCH_F4;
        const float4* srcv = dir ? base : (base + NVP);   // gt4 : rec4p
        const float4* tgtv = dir ? (base + NVP) : base;   // rec4p : gt4
        for (int j = tid; j < NVP; j += 256) s_t[j] = tgtv[j];
        if (tid == 0) s_red[0] = 0.0f;
        __syncthreads();

        const int CPT = 4;
        float nax[CPT], nay[CPT], naz[CPT], a2[CPT], m[CPT];
        bool valid[CPT];
#pragma unroll
        for (int k = 0; k < CPT; ++k) {
            int p = tid + 256 * k;
            valid[k] = (p < NV);
            float4 s = srcv[valid[k] ? p : 0];
            nax[k] = -2.0f * s.x; nay[k] = -2.0f * s.y; naz[k] = -2.0f * s.z;
            a2[k] = s.w;                  // one of src/tgt carries +BIAS
            m[k] = 3.4e38f;
        }
#pragma unroll 1
        for (int j = 0; j < NVP; j += 4) {
            float4 t0 = s_t[j], t1 = s_t[j+1], t2 = s_t[j+2], t3 = s_t[j+3];
#pragma unroll
            for (int k = 0; k < CPT; ++k) {
                float d0 = fmaf(nax[k], t0.x, fmaf(nay[k], t0.y, fmaf(naz[k], t0.z, t0.w)));
                float d1 = fmaf(nax[k], t1.x, fmaf(nay[k], t1.y, fmaf(naz[k], t1.z, t1.w)));
                float d2 = fmaf(nax[k], t2.x, fmaf(nay[k], t2.y, fmaf(naz[k], t2.z, t2.w)));
                float d3 = fmaf(nax[k], t3.x, fmaf(nay[k], t3.y, fmaf(naz[k], t3.z, t3.w)));
                m[k] = fminf(fminf(m[k], fminf(d0, d1)), fminf(d2, d3));
            }
        }
        float local = 0.0f;
#pragma unroll
        for (int k = 0; k < CPT; ++k)
            if (valid[k]) local += fmaxf(a2[k] + m[k] - BIAS, 0.0f);
        atomicAdd(&s_red[0], local);
        __syncthreads();
        if (tid == 0) atomicAdd(&acc[2], s_red[0]);
    }
}

// ---------------- Combine (popcount rc&gc) + finalize (ticket) ----------------
__global__ __launch_bounds__(256) void k_combine(float* __restrict__ acc,
                                                 const unsigned int* __restrict__ rcW,
                                                 const unsigned int* __restrict__ gcW,
                                                 const float* __restrict__ mean,
                                                 const float* __restrict__ log_var,
                                                 const float* __restrict__ rp,
                                                 const float* __restrict__ xp,
                                                 float* __restrict__ out) {
    int blk = blockIdx.x, tid = threadIdx.x;
    __shared__ float s_red[2];
    __shared__ unsigned int s_ticket;
    if (tid < 2) s_red[tid] = 0.0f;
    __syncthreads();
    int idx = blk * 256 + tid;                    // 16384 uints = NPTS/8 bytes
    unsigned int rc = rcW[idx], gc = gcW[idx];
    float cnt = (float)__popc(rc & gc);
    atomicAdd(&s_red[0], cnt);
    __syncthreads();
    if (tid == 0) atomicAdd(&acc[6], s_red[0]);
    __threadfence();
    if (tid == 0) s_ticket = atomicAdd((unsigned int*)&acc[15], 1u);
    __syncthreads();

    if (s_ticket == CMB_BLOCKS - 1) {
        if (tid < 2) s_red[tid] = 0.0f;
        __syncthreads();
        float s_param = 0.0f, s_kld = 0.0f;
        for (int i = tid; i < NB * NPAR; i += 256) {
            float d = rp[i] - xp[i];
            s_param += d * d;
        }
        for (int i = tid; i < NB * NZ; i += 256) {
            float m = mean[i], lv = log_var[i];
            s_kld += 1.0f + lv - m * m - expf(lv);
        }
        atomicAdd(&s_red[0], s_param);
        atomicAdd(&s_red[1], s_kld);
        __syncthreads();
        if (tid == 0) {
            const float fB = 64.0f;
            float a2v = atomicAdd(&acc[2], 0.0f);
            float a3  = atomicAdd(&acc[3], 0.0f);
            float a4  = atomicAdd(&acc[4], 0.0f);
            float a5  = atomicAdd(&acc[5], 0.0f);
            float a6  = atomicAdd(&acc[6], 0.0f);
            float a7  = atomicAdd(&acc[7], 0.0f);
            float param_loss  = s_red[0] / fB;
            float KLD         = -0.5f * s_red[1] / fB * 10.0f;
            float recon_loss  = a2v / fB;
            float cmap_loss   = 3000.0f * a3 / (fB * a4);
            float consistency = -5.0f * a6 / (a5 + 0.0001f);
            float penetr      = 100.0f * a7 / fB;
            out[0] = (recon_loss + KLD) + 0.1f * param_loss + 1000.0f * cmap_loss
                   + 10.0f * consistency + 10.0f * penetr;
        }
    }
}

extern "C" void kernel_launch(void* const* d_in, const int* in_sizes, int n_in,
                              void* d_out, int out_size, void* d_ws, size_t ws_size,
                              hipStream_t stream) {
    (void)in_sizes; (void)n_in; (void)out_size; (void)ws_size;
    const float* obj     = (const float*)d_in[0];
    const float* recon   = (const float*)d_in[1];
    const float* gt      = (const float*)d_in[2];
    const float* mean    = (const float*)d_in[3];
    const float* log_var = (const float*)d_in[4];
    const float* rp      = (const float*)d_in[5];
    const float* xp      = (const float*)d_in[6];
    const int*   faces   = (const int*)d_in[7];
    float4* ws4 = (float4*)d_ws;
    float* acc  = (float*)d_ws + ACC_OFF;
    unsigned char* rcA = (unsigned char*)((float*)d_ws + RC_OFF);
    unsigned char* gcA = (unsigned char*)((float*)d_ws + GC_OFF);
    float* out  = (float*)d_out;

    k_prep   <<<NB,           256, 0, stream>>>(recon, gt, faces, ws4, acc);
    k_fused  <<<NROLE_BLOCKS, 256, 0, stream>>>(obj, ws4, acc, rcA, gcA);
    k_combine<<<CMB_BLOCKS,   256, 0, stream>>>(acc, (const unsigned int*)rcA,
                                                (const unsigned int*)gcA,
                                                mean, log_var, rp, xp, out);
}